// Round 1
// baseline (755.695 us; speedup 1.0000x reference)
//
#include <hip/hip_runtime.h>
#include <math.h>

#define NPTS 131072
#define NSPA 256
#define NC 128  // channels per direction (DF*8)

__device__ __forceinline__ float dev_alpha(const float* __restrict__ ap) {
    float x = ap[0];
    float bx = 10.0f * x;
    if (bx > 1.0f) return x;
    float e = expf(fminf(bx, 30.0f));
    return 0.1f * log1pf(e);
}

// ---------------- pass1: FFT along axis B (innermost spectral), write GT[c][b][a] ----------------
// Block: 16 rows (same channel c = f*8+d, consecutive a = a0..a0+15), 256 threads.
// Grid: 2048 blocks: bg -> d = bg&7, ag = (bg>>3)&15, f = bg>>7.
__global__ __launch_bounds__(256) void fft_pass1(
    const float* __restrict__ Fre, const float* __restrict__ Fim,
    const float* __restrict__ alpha_p,
    float2* __restrict__ GT,
    int Sd, int Sa, int Sb)
{
    __shared__ float lre[16 * 256];
    __shared__ float lim[16 * 256];
    __shared__ float twc[256];
    __shared__ float tws[256];

    const int tid = threadIdx.x;
    const int bg  = blockIdx.x;
    const int d   = bg & 7;
    const int ag  = (bg >> 3) & 15;
    const int f   = bg >> 7;
    const int a0  = ag * 16;
    const int c   = f * 8 + d;
    const int base = f * 524288 + d * Sd + a0 * Sa;

    const float alpha = dev_alpha(alpha_p);

    // twiddle table: tw[h+j] = exp(+i*pi*j/h), indices 1..255
    if (tid > 0) {
        int h = 1 << (31 - __clz(tid));
        int j = tid - h;
        float ang = 3.14159265358979323846f * (float)j / (float)h;
        float s, co;
        __sincosf(ang, &s, &co);
        twc[tid] = co; tws[tid] = s;
    }

    // load (bit-reversed along b), scale by alpha
    for (int i = tid; i < 4096; i += 256) {
        int ar = i >> 8, b = i & 255;
        int addr = base + ar * Sa + b * Sb;
        int dst = ar * 256 + (int)(__brev((unsigned)b) >> 24);
        lre[dst] = Fre[addr] * alpha;
        lim[dst] = Fim[addr] * alpha;
    }
    __syncthreads();

    // radix-2 DIT, e^{+i} (inverse, norm='forward' => unscaled)
    for (int half = 1; half < 256; half <<= 1) {
        for (int i = tid; i < 2048; i += 256) {
            int row = i >> 7, bb = i & 127;
            int j  = bb & (half - 1);
            int i0 = row * 256 + 2 * bb - j;
            int i1 = i0 + half;
            float wc = twc[half + j], ws = tws[half + j];
            float xr = lre[i1], xi = lim[i1];
            float tr = wc * xr - ws * xi;
            float ti = wc * xi + ws * xr;
            float ur = lre[i0], ui = lim[i0];
            lre[i1] = ur - tr; lim[i1] = ui - ti;
            lre[i0] = ur + tr; lim[i0] = ui + ti;
        }
        __syncthreads();
    }

    // write GT[c][b][a0+r]  (128B segments, coalesced)
    for (int i = tid; i < 4096; i += 256) {
        int b = i >> 4, r = i & 15;
        GT[(c * 256 + b) * 256 + a0 + r] = make_float2(lre[r * 256 + b], lim[r * 256 + b]);
    }
}

// ---------------- pass2: FFT along axis A, write V[b][t][c] (c fastest) ----------------
// Block: 16 channels (c0..c0+15) for one b. Grid 2048: bg -> cg = bg&7, b = bg>>3.
__global__ __launch_bounds__(256) void fft_pass2(
    const float2* __restrict__ GT,
    float2* __restrict__ V)
{
    __shared__ float lre[16 * 256];
    __shared__ float lim[16 * 256];
    __shared__ float twc[256];
    __shared__ float tws[256];

    const int tid = threadIdx.x;
    const int bg  = blockIdx.x;
    const int cg  = bg & 7;
    const int b   = bg >> 3;
    const int c0  = cg * 16;

    if (tid > 0) {
        int h = 1 << (31 - __clz(tid));
        int j = tid - h;
        float ang = 3.14159265358979323846f * (float)j / (float)h;
        float s, co;
        __sincosf(ang, &s, &co);
        twc[tid] = co; tws[tid] = s;
    }

    for (int i = tid; i < 4096; i += 256) {
        int cr = i >> 8, a = i & 255;
        float2 v = GT[((c0 + cr) * 256 + b) * 256 + a];
        int dst = cr * 256 + (int)(__brev((unsigned)a) >> 24);
        lre[dst] = v.x; lim[dst] = v.y;
    }
    __syncthreads();

    for (int half = 1; half < 256; half <<= 1) {
        for (int i = tid; i < 2048; i += 256) {
            int row = i >> 7, bb = i & 127;
            int j  = bb & (half - 1);
            int i0 = row * 256 + 2 * bb - j;
            int i1 = i0 + half;
            float wc = twc[half + j], ws = tws[half + j];
            float xr = lre[i1], xi = lim[i1];
            float tr = wc * xr - ws * xi;
            float ti = wc * xi + ws * xr;
            float ur = lre[i0], ui = lim[i0];
            lre[i1] = ur - tr; lim[i1] = ui - ti;
            lre[i0] = ur + tr; lim[i0] = ui + ti;
        }
        __syncthreads();
    }

    // write V[(b*256 + t)*128 + c]  (128B segments)
    for (int i = tid; i < 4096; i += 256) {
        int t = i >> 4, cr = i & 15;
        V[(b * 256 + t) * 128 + c0 + cr] = make_float2(lre[cr * 256 + t], lim[cr * 256 + t]);
    }
}

// ---------------- sampler: one wave per point, bilinear + 8-freq irDFT, accumulate ----------------
__global__ __launch_bounds__(256) void sample_acc(
    const float4* __restrict__ Vf4,   // V as float4: [rec][64] (2 complex per lane)
    const float* __restrict__ pts,    // [N][3]
    float* __restrict__ out,          // [N][16]
    int gyIdx, int gxIdx, int twIdx,
    int recSwap, int accumulate)
{
    const int wid  = (int)((blockIdx.x * blockDim.x + threadIdx.x) >> 6);
    const int lane = threadIdx.x & 63;
    if (wid >= NPTS) return;

    const float gx = pts[wid * 3 + gxIdx];
    const float gy = pts[wid * 3 + gyIdx];
    const float tw = pts[wid * 3 + twIdx];

    const float ix = (gx + 1.0f) * 0.5f * 255.0f;
    const float iy = (gy + 1.0f) * 0.5f * 255.0f;
    const float x0f = floorf(ix), y0f = floorf(iy);
    const float wx = ix - x0f,  wy = iy - y0f;
    int x0 = min(max((int)x0f, 0), 255);
    int x1 = min(x0 + 1, 255);
    int y0 = min(max((int)y0f, 0), 255);
    int y1 = min(y0 + 1, 255);

    int r00, r01, r10, r11;
    if (recSwap) { // rec = y*256 + x
        r00 = y0 * 256 + x0; r01 = y0 * 256 + x1;
        r10 = y1 * 256 + x0; r11 = y1 * 256 + x1;
    } else {       // rec = x*256 + y
        r00 = x0 * 256 + y0; r01 = x1 * 256 + y0;
        r10 = x0 * 256 + y1; r11 = x1 * 256 + y1;
    }
    const float w00 = (1.0f - wy) * (1.0f - wx);
    const float w01 = (1.0f - wy) * wx;
    const float w10 = wy * (1.0f - wx);
    const float w11 = wy * wx;

    float s0r = 0.f, s0i = 0.f, s1r = 0.f, s1i = 0.f;
    float4 v;
    v = Vf4[r00 * 64 + lane]; s0r += w00 * v.x; s0i += w00 * v.y; s1r += w00 * v.z; s1i += w00 * v.w;
    v = Vf4[r01 * 64 + lane]; s0r += w01 * v.x; s0i += w01 * v.y; s1r += w01 * v.z; s1i += w01 * v.w;
    v = Vf4[r10 * 64 + lane]; s0r += w10 * v.x; s0i += w10 * v.y; s1r += w10 * v.z; s1i += w10 * v.w;
    v = Vf4[r11 * 64 + lane]; s0r += w11 * v.x; s0i += w11 * v.y; s1r += w11 * v.z; s1i += w11 * v.w;

    // irDFT twiddles: lane handles k0 = (lane&3)*2 and k0+1
    const float xx = (tw + 1.0f) * 0.5f * (255.0f / 256.0f);
    const int k0 = (lane & 3) * 2;
    const float TWO_PI = 6.28318530717958647692f;
    float sa, ca, sb, cb;
    __sincosf(TWO_PI * xx * (float)k0,       &sa, &ca);
    __sincosf(TWO_PI * xx * (float)(k0 + 1), &sb, &cb);
    const float sc0 = (k0 > 0) ? 2.0f : 1.0f;

    float p = sc0 * (s0r * ca - s0i * sa) + 2.0f * (s1r * cb - s1i * sb);
    p += __shfl_xor(p, 1, 64);
    p += __shfl_xor(p, 2, 64);

    if ((lane & 3) == 0) {
        int fidx = lane >> 2;
        float* o = out + wid * 16 + fidx;
        if (accumulate) *o += p; else *o = p;
    }
}

extern "C" void kernel_launch(void* const* d_in, const int* in_sizes, int n_in,
                              void* d_out, int out_size, void* d_ws, size_t ws_size,
                              hipStream_t stream) {
    const float* pts     = (const float*)d_in[0];
    const float* Fx_re   = (const float*)d_in[1];
    const float* Fx_im   = (const float*)d_in[2];
    const float* Fy_re   = (const float*)d_in[3];
    const float* Fy_im   = (const float*)d_in[4];
    const float* Fz_re   = (const float*)d_in[5];
    const float* Fz_im   = (const float*)d_in[6];
    const float* alpha_p = (const float*)d_in[7];
    float* out = (float*)d_out;

    float2* V  = (float2*)d_ws;                                    // 64 MiB
    float2* GT = (float2*)((char*)d_ws + (size_t)64 * 1024 * 1024); // 64 MiB

    struct DirCfg { const float* re; const float* im; int Sd, Sa, Sb; int gy, gx, tw; int recSwap; };
    // dir x: F[f][d][ky][kz]: Sd=65536, Sa(ky)=256, Sb(kz)=1; sample gy=ys(1), gx=zs(2), tw=xs(0); rec=ix*256+iy
    // dir y: F[f][kx][d][kz]: Sd=256,   Sa(kx)=2048, Sb(kz)=1; gy=xs(0), gx=zs(2), tw=ys(1); rec=ix*256+iy
    // dir z: F[f][kx][ky][d]: Sd=1,     Sa(kx)=2048, Sb(ky)=8; gy=ys(1), gx=xs(0), tw=zs(2); rec=iy*256+ix
    DirCfg dirs[3] = {
        { Fx_re, Fx_im, 65536, 256,  1, 1, 2, 0, 0 },
        { Fy_re, Fy_im, 256,   2048, 1, 0, 2, 1, 0 },
        { Fz_re, Fz_im, 1,     2048, 8, 1, 0, 2, 1 },
    };

    for (int dir = 0; dir < 3; ++dir) {
        fft_pass1<<<2048, 256, 0, stream>>>(dirs[dir].re, dirs[dir].im, alpha_p, GT,
                                            dirs[dir].Sd, dirs[dir].Sa, dirs[dir].Sb);
        fft_pass2<<<2048, 256, 0, stream>>>(GT, V);
        sample_acc<<<NPTS / 4, 256, 0, stream>>>((const float4*)V, pts, out,
                                                 dirs[dir].gy, dirs[dir].gx, dirs[dir].tw,
                                                 dirs[dir].recSwap, dir > 0);
    }
}

// Round 2
// 493.339 us; speedup vs baseline: 1.5318x; 1.5318x over previous
//
#include <hip/hip_runtime.h>
#include <hip/hip_fp16.h>
#include <math.h>

#define NPTS 131072
#define LS 259  // LDS row stride (259 mod 32 = 3 -> banks spread by 3*row)

__device__ __forceinline__ float dev_alpha(const float* __restrict__ ap) {
    float x = ap[0];
    float bx = 10.0f * x;
    if (bx > 1.0f) return x;
    float e = expf(fminf(bx, 30.0f));
    return 0.1f * log1pf(e);
}

// twiddle table: tw[h+j] = exp(+i*pi*j/h), indices 1..255
__device__ __forceinline__ void init_tw(float* twc, float* tws, int tid) {
    if (tid > 0) {
        int h = 1 << (31 - __clz(tid));
        int j = tid - h;
        float ang = 3.14159265358979323846f * (float)j / (float)h;
        float s, c;
        __sincosf(ang, &s, &c);
        twc[tid] = c; tws[tid] = s;
    }
}

// Inverse-DFT DIF over 16 rows x 256 (natural-order input, bit-reversed output:
// physical pos p holds X[brev8(p)]). Caller must __syncthreads() before.
__device__ __forceinline__ void dif_fft(float* lre, float* lim,
                                        const float* twc, const float* tws, int tid) {
    for (int half = 128; half >= 1; half >>= 1) {
        for (int i = tid; i < 2048; i += 256) {
            int row = i >> 7, bb = i & 127;
            int j  = bb & (half - 1);
            int p  = 2 * bb - j;
            int i0 = row * LS + p;
            int i1 = i0 + half;
            float ur = lre[i0], ui = lim[i0];
            float vr = lre[i1], vi = lim[i1];
            float wc = twc[half + j], ws = tws[half + j];
            float dr = ur - vr, di = ui - vi;
            lre[i0] = ur + vr;          lim[i0] = ui + vi;
            lre[i1] = dr * wc - di * ws; lim[i1] = dr * ws + di * wc;
        }
        __syncthreads();
    }
}

// ---------------- pass1 (dirs x,y; Sb==1): FFT along innermost b, GT[c][b][a] fp16 ----------------
__global__ __launch_bounds__(256) void fft_pass1_xy(
    const float* __restrict__ Fre, const float* __restrict__ Fim,
    const float* __restrict__ alpha_p, __half2* __restrict__ GT,
    int Sd, int Sa)
{
    __shared__ float lre[16 * LS], lim[16 * LS];
    __shared__ float twc[256], tws[256];
    const int tid = threadIdx.x, bg = blockIdx.x;
    const int d = bg & 7, ag = (bg >> 3) & 15, f = bg >> 7;
    const int a0 = ag * 16, c = f * 8 + d;
    const int base = f * 524288 + d * Sd + a0 * Sa;
    const float alpha = dev_alpha(alpha_p);
    init_tw(twc, tws, tid);
    for (int i = tid; i < 4096; i += 256) {
        int ar = i >> 8, b = i & 255;
        int addr = base + ar * Sa + b;
        lre[ar * LS + b] = Fre[addr] * alpha;
        lim[ar * LS + b] = Fim[addr] * alpha;
    }
    __syncthreads();
    dif_fft(lre, lim, twc, tws, tid);
    for (int i = tid; i < 4096; i += 256) {
        int b = i >> 4, r = i & 15;
        int src = r * LS + (int)(__brev((unsigned)b) >> 24);
        GT[(c * 256 + b) * 256 + a0 + r] = __floats2half2_rn(lre[src], lim[src]);
    }
}

// ---------------- pass2 (dirs x,y): FFT along a of GT[c][b][a], V[b][t][c] fp16 ----------------
__global__ __launch_bounds__(256) void fft_pass2_xy(
    const __half2* __restrict__ GT, __half2* __restrict__ V)
{
    __shared__ float lre[16 * LS], lim[16 * LS];
    __shared__ float twc[256], tws[256];
    const int tid = threadIdx.x, bg = blockIdx.x;
    const int cg = bg & 7, b = bg >> 3, c0 = cg * 16;
    init_tw(twc, tws, tid);
    for (int i = tid; i < 4096; i += 256) {
        int cr = i >> 8, a = i & 255;
        float2 v = __half22float2(GT[((c0 + cr) * 256 + b) * 256 + a]);
        lre[cr * LS + a] = v.x;
        lim[cr * LS + a] = v.y;
    }
    __syncthreads();
    dif_fft(lre, lim, twc, tws, tid);
    for (int i = tid; i < 4096; i += 256) {
        int t = i >> 4, cr = i & 15;
        int src = cr * LS + (int)(__brev((unsigned)t) >> 24);
        V[(b * 256 + t) * 128 + c0 + cr] = __floats2half2_rn(lre[src], lim[src]);
    }
}

// ---------------- dir z pass1: Fz[f][kx][ky][d] -> FFT along ky -> GTz[b][f][kx][d] ----------------
// Block: (f, kx-pair). Loads one contiguous 16KB span. 2048 blocks.
__global__ __launch_bounds__(256) void fft_pass1_z(
    const float* __restrict__ Fre, const float* __restrict__ Fim,
    const float* __restrict__ alpha_p, __half2* __restrict__ GTz)
{
    __shared__ float lre[16 * LS], lim[16 * LS];
    __shared__ float twc[256], tws[256];
    const int tid = threadIdx.x, bg = blockIdx.x;
    const int f = bg >> 7, kxp = bg & 127;
    const int base = f * 524288 + kxp * 4096;
    const float alpha = dev_alpha(alpha_p);
    init_tw(twc, tws, tid);
    for (int i = tid; i < 4096; i += 256) {
        int kxo = i >> 11, rem = i & 2047;
        int ky = rem >> 3, d = rem & 7;
        int row = kxo * 8 + d;
        lre[row * LS + ky] = Fre[base + i] * alpha;
        lim[row * LS + ky] = Fim[base + i] * alpha;
    }
    __syncthreads();
    dif_fft(lre, lim, twc, tws, tid);
    // GTz[b][f][kx][d]: addr = b*32768 + f*2048 + (kxp*2+kxo)*8 + d = b*32768 + f*2048 + kxp*16 + r
    for (int i = tid; i < 4096; i += 256) {
        int b = i >> 4, r = i & 15;
        int src = r * LS + (int)(__brev((unsigned)b) >> 24);
        GTz[b * 32768 + f * 2048 + kxp * 16 + r] = __floats2half2_rn(lre[src], lim[src]);
    }
}

// ---------------- dir z pass2: GTz[b][f][kx][d] -> FFT along kx -> Vz[(b*256+t)*128+c] ----------------
// Block: (b, f-pair). Loads one contiguous 16KB span. 2048 blocks.
__global__ __launch_bounds__(256) void fft_pass2_z(
    const __half2* __restrict__ GTz, __half2* __restrict__ Vz)
{
    __shared__ float lre[16 * LS], lim[16 * LS];
    __shared__ float twc[256], tws[256];
    const int tid = threadIdx.x, bg = blockIdx.x;
    const int fp = bg & 7, b = bg >> 3;
    const int base = b * 32768 + fp * 4096;
    init_tw(twc, tws, tid);
    for (int i = tid; i < 4096; i += 256) {
        int fo = i >> 11, rem = i & 2047;
        int kx = rem >> 3, d = rem & 7;
        int row = fo * 8 + d;
        float2 v = __half22float2(GTz[base + i]);
        lre[row * LS + kx] = v.x;
        lim[row * LS + kx] = v.y;
    }
    __syncthreads();
    dif_fft(lre, lim, twc, tws, tid);
    // channel c = (fp*2+fo)*8 + d = fp*16 + r
    for (int i = tid; i < 4096; i += 256) {
        int t = i >> 4, r = i & 15;
        int src = r * LS + (int)(__brev((unsigned)t) >> 24);
        Vz[(b * 256 + t) * 128 + fp * 16 + r] = __floats2half2_rn(lre[src], lim[src]);
    }
}

// ---------------- fused sampler: one wave per point, all 3 directions ----------------
__device__ __forceinline__ float4 bsample(const uint2* __restrict__ V,
                                          float gx, float gy, bool swap, int lane) {
    float ix = (gx + 1.0f) * 127.5f;
    float iy = (gy + 1.0f) * 127.5f;
    float x0f = floorf(ix), y0f = floorf(iy);
    float wx = ix - x0f, wy = iy - y0f;
    int x0 = min(max((int)x0f, 0), 255);
    int x1 = min(x0 + 1, 255);
    int y0 = min(max((int)y0f, 0), 255);
    int y1 = min(y0 + 1, 255);
    int rA, rB, rC, rD;
    if (swap) { rA = y0 * 256 + x0; rB = y0 * 256 + x1; rC = y1 * 256 + x0; rD = y1 * 256 + x1; }
    else      { rA = x0 * 256 + y0; rB = x1 * 256 + y0; rC = x0 * 256 + y1; rD = x1 * 256 + y1; }
    float w00 = (1.0f - wy) * (1.0f - wx);
    float w01 = (1.0f - wy) * wx;
    float w10 = wy * (1.0f - wx);
    float w11 = wy * wx;
    uint2 a = V[rA * 64 + lane];
    uint2 b = V[rB * 64 + lane];
    uint2 cc = V[rC * 64 + lane];
    uint2 dd = V[rD * 64 + lane];
    float4 s = make_float4(0.f, 0.f, 0.f, 0.f);
    float2 f0, f1;
    f0 = __half22float2(__builtin_bit_cast(__half2, a.x));  f1 = __half22float2(__builtin_bit_cast(__half2, a.y));
    s.x += w00 * f0.x; s.y += w00 * f0.y; s.z += w00 * f1.x; s.w += w00 * f1.y;
    f0 = __half22float2(__builtin_bit_cast(__half2, b.x));  f1 = __half22float2(__builtin_bit_cast(__half2, b.y));
    s.x += w01 * f0.x; s.y += w01 * f0.y; s.z += w01 * f1.x; s.w += w01 * f1.y;
    f0 = __half22float2(__builtin_bit_cast(__half2, cc.x)); f1 = __half22float2(__builtin_bit_cast(__half2, cc.y));
    s.x += w10 * f0.x; s.y += w10 * f0.y; s.z += w10 * f1.x; s.w += w10 * f1.y;
    f0 = __half22float2(__builtin_bit_cast(__half2, dd.x)); f1 = __half22float2(__builtin_bit_cast(__half2, dd.y));
    s.x += w11 * f0.x; s.y += w11 * f0.y; s.z += w11 * f1.x; s.w += w11 * f1.y;
    return s;
}

__device__ __forceinline__ float irdft(float4 s, float tw, int lane) {
    const float TWO_PI = 6.28318530717958647692f;
    float xx = (tw + 1.0f) * 0.5f * (255.0f / 256.0f);
    int k0 = (lane & 3) * 2;
    float sa, ca, sb, cb;
    __sincosf(TWO_PI * xx * (float)k0,       &sa, &ca);
    __sincosf(TWO_PI * xx * (float)(k0 + 1), &sb, &cb);
    float sc0 = (k0 > 0) ? 2.0f : 1.0f;
    return sc0 * (s.x * ca - s.y * sa) + 2.0f * (s.z * cb - s.w * sb);
}

__global__ __launch_bounds__(256) void sample_all(
    const uint2* __restrict__ Vx, const uint2* __restrict__ Vy, const uint2* __restrict__ Vz,
    const float* __restrict__ pts, float* __restrict__ out)
{
    const int wid  = (int)((blockIdx.x * blockDim.x + threadIdx.x) >> 6);
    const int lane = threadIdx.x & 63;
    if (wid >= NPTS) return;
    const float xs = pts[wid * 3 + 0];
    const float ys = pts[wid * 3 + 1];
    const float zs = pts[wid * 3 + 2];

    // dir x: V[(z*256+y)*128+c], gx=zs, gy=ys, tw=xs
    float4 sx = bsample(Vx, zs, ys, false, lane);
    // dir y: V[(z*256+x)*128+c], gx=zs, gy=xs, tw=ys
    float4 sy = bsample(Vy, zs, xs, false, lane);
    // dir z: V[(y*256+x)*128+c], gx=xs, gy=ys (swap), tw=zs
    float4 sz = bsample(Vz, xs, ys, true, lane);

    float p = irdft(sx, xs, lane) + irdft(sy, ys, lane) + irdft(sz, zs, lane);
    p += __shfl_xor(p, 1, 64);
    p += __shfl_xor(p, 2, 64);
    if ((lane & 3) == 0) out[wid * 16 + (lane >> 2)] = p;
}

extern "C" void kernel_launch(void* const* d_in, const int* in_sizes, int n_in,
                              void* d_out, int out_size, void* d_ws, size_t ws_size,
                              hipStream_t stream) {
    const float* pts     = (const float*)d_in[0];
    const float* Fx_re   = (const float*)d_in[1];
    const float* Fx_im   = (const float*)d_in[2];
    const float* Fy_re   = (const float*)d_in[3];
    const float* Fy_im   = (const float*)d_in[4];
    const float* Fz_re   = (const float*)d_in[5];
    const float* Fz_im   = (const float*)d_in[6];
    const float* alpha_p = (const float*)d_in[7];
    float* out = (float*)d_out;

    char* ws = (char*)d_ws;
    __half2* Vx = (__half2*)(ws);                            // 32 MiB
    __half2* Vy = (__half2*)(ws + (size_t)32 * 1024 * 1024); // 32 MiB
    __half2* Vz = (__half2*)(ws + (size_t)64 * 1024 * 1024); // 32 MiB
    __half2* GT = (__half2*)(ws + (size_t)96 * 1024 * 1024); // 32 MiB (reused per dir)

    // dir x: F[f][d][ky][kz]: Sd=65536, Sa(ky)=256 ; pass1 FFT kz, pass2 FFT ky
    fft_pass1_xy<<<2048, 256, 0, stream>>>(Fx_re, Fx_im, alpha_p, GT, 65536, 256);
    fft_pass2_xy<<<2048, 256, 0, stream>>>(GT, Vx);
    // dir y: F[f][kx][d][kz]: Sd=256, Sa(kx)=2048 ; pass1 FFT kz, pass2 FFT kx
    fft_pass1_xy<<<2048, 256, 0, stream>>>(Fy_re, Fy_im, alpha_p, GT, 256, 2048);
    fft_pass2_xy<<<2048, 256, 0, stream>>>(GT, Vy);
    // dir z: specialized contiguous-load kernels
    fft_pass1_z<<<2048, 256, 0, stream>>>(Fz_re, Fz_im, alpha_p, GT);
    fft_pass2_z<<<2048, 256, 0, stream>>>(GT, Vz);

    sample_all<<<NPTS / 4, 256, 0, stream>>>((const uint2*)Vx, (const uint2*)Vy, (const uint2*)Vz,
                                             pts, out);
}

// Round 3
// 430.232 us; speedup vs baseline: 1.7565x; 1.1467x over previous
//
#include <hip/hip_runtime.h>
#include <hip/hip_fp16.h>
#include <math.h>

#define NPTS 131072
#define RS 265      // LDS row stride in floats (265 mod 32 = 9 -> rows spread banks by 9)
#define NBIN 65536

__device__ __forceinline__ float dev_alpha(const float* __restrict__ ap) {
    float x = ap[0];
    float bx = 10.0f * x;
    if (bx > 1.0f) return x;
    float e = expf(fminf(bx, 30.0f));
    return 0.1f * log1pf(e);
}

// -------- 16-point inverse DFT (e^{+i}) in registers, natural in/out --------
__device__ __forceinline__ void fft16_reg(float* re, float* im) {
    // bit-reverse (4-bit): swap (1,8)(2,4)(3,12)(5,10)(7,14)(11,13)
    #define SW(a,b) { float t=re[a]; re[a]=re[b]; re[b]=t; t=im[a]; im[a]=im[b]; im[b]=t; }
    SW(1,8) SW(2,4) SW(3,12) SW(5,10) SW(7,14) SW(11,13)
    #undef SW
    const float C[8] = {1.f, 0.9238795325112867f, 0.7071067811865476f, 0.3826834323650898f,
                        0.f, -0.3826834323650898f, -0.7071067811865476f, -0.9238795325112867f};
    const float S[8] = {0.f, 0.3826834323650898f, 0.7071067811865476f, 0.9238795325112867f,
                        1.f, 0.9238795325112867f, 0.7071067811865476f, 0.3826834323650898f};
    #pragma unroll
    for (int m = 1; m < 16; m <<= 1) {
        #pragma unroll
        for (int k = 0; k < 16; k += 2 * m) {
            #pragma unroll
            for (int j = 0; j < m; ++j) {
                float wc = C[j * (8 / m)], ws = S[j * (8 / m)];
                int i0 = k + j, i1 = i0 + m;
                float tr = re[i1] * wc - im[i1] * ws;
                float ti = re[i1] * ws + im[i1] * wc;
                re[i1] = re[i0] - tr; im[i1] = im[i0] - ti;
                re[i0] += tr;         im[i0] += ti;
            }
        }
    }
}

// -------- 256-pt inverse FFT over 16 rows staged in LDS (natural in, natural out) --------
// Thread (r = tid>>4, s = tid&15). Requires data already in lds[row*RS + n], caller synced.
__device__ __forceinline__ void fft256_block(float* lre, float* lim, int tid) {
    const int r = tid >> 4, s = tid & 15;
    float xr[16], xi[16];
    #pragma unroll
    for (int a = 0; a < 16; ++a) {
        xr[a] = lre[r * RS + 16 * a + s];
        xi[a] = lim[r * RS + 16 * a + s];
    }
    __syncthreads();
    fft16_reg(xr, xi);
    // middle twiddle e^{+2pi i * s * c / 256}, XOR-swizzled store (<=2-way banks)
    #pragma unroll
    for (int c = 0; c < 16; ++c) {
        float sn, cs;
        __sincosf(0.0245436926061703f * (float)(s * c), &sn, &cs); // 2*pi/256
        float tr = xr[c] * cs - xi[c] * sn;
        float ti = xr[c] * sn + xi[c] * cs;
        int idx = r * RS + 16 * c + (s ^ c);
        lre[idx] = tr; lim[idx] = ti;
    }
    __syncthreads();
    #pragma unroll
    for (int b = 0; b < 16; ++b) {
        int idx = r * RS + 16 * s + (b ^ s);
        xr[b] = lre[idx]; xi[b] = lim[idx];
    }
    __syncthreads();
    fft16_reg(xr, xi);
    // X[s + 16 d] -> natural position
    #pragma unroll
    for (int d = 0; d < 16; ++d) {
        int idx = r * RS + 16 * d + s;
        lre[idx] = xr[d]; lim[idx] = xi[d];
    }
    __syncthreads();
}

// ---------------- pass1 (dirs x,y; innermost stride 1): FFT along b, GT[c][b][a] fp16 ----------------
__global__ __launch_bounds__(256) void fft_pass1_xy(
    const float* __restrict__ Fre, const float* __restrict__ Fim,
    const float* __restrict__ alpha_p, __half2* __restrict__ GT,
    int Sd, int Sa)
{
    __shared__ float lre[16 * RS], lim[16 * RS];
    const int tid = threadIdx.x, bg = blockIdx.x;
    const int d = bg & 7, ag = (bg >> 3) & 15, f = bg >> 7;
    const int a0 = ag * 16, c = f * 8 + d;
    const int base = f * 524288 + d * Sd + a0 * Sa;
    const float alpha = dev_alpha(alpha_p);
    for (int i = tid; i < 4096; i += 256) {
        int ar = i >> 8, b = i & 255;
        int addr = base + ar * Sa + b;
        lre[ar * RS + b] = Fre[addr] * alpha;
        lim[ar * RS + b] = Fim[addr] * alpha;
    }
    __syncthreads();
    fft256_block(lre, lim, tid);
    for (int i = tid; i < 4096; i += 256) {
        int k = i >> 4, rr = i & 15;
        GT[(c * 256 + k) * 256 + a0 + rr] = __floats2half2_rn(lre[rr * RS + k], lim[rr * RS + k]);
    }
}

// ---------------- pass2 (dirs x,y): FFT along a of GT[c][b][a], V[b][t][c] fp16 ----------------
__global__ __launch_bounds__(256) void fft_pass2_xy(
    const __half2* __restrict__ GT, __half2* __restrict__ V)
{
    __shared__ float lre[16 * RS], lim[16 * RS];
    const int tid = threadIdx.x, bg = blockIdx.x;
    const int cg = bg & 7, b = bg >> 3, c0 = cg * 16;
    for (int i = tid; i < 4096; i += 256) {
        int cr = i >> 8, a = i & 255;
        float2 v = __half22float2(GT[((c0 + cr) * 256 + b) * 256 + a]);
        lre[cr * RS + a] = v.x;
        lim[cr * RS + a] = v.y;
    }
    __syncthreads();
    fft256_block(lre, lim, tid);
    for (int i = tid; i < 4096; i += 256) {
        int k = i >> 4, cr = i & 15;
        V[(b * 256 + k) * 128 + c0 + cr] = __floats2half2_rn(lre[cr * RS + k], lim[cr * RS + k]);
    }
}

// ---------------- dir z pass1: Fz[f][kx][ky][d] -> FFT along ky -> GTz[b][f][kx][d] ----------------
__global__ __launch_bounds__(256) void fft_pass1_z(
    const float* __restrict__ Fre, const float* __restrict__ Fim,
    const float* __restrict__ alpha_p, __half2* __restrict__ GTz)
{
    __shared__ float lre[16 * RS], lim[16 * RS];
    const int tid = threadIdx.x, bg = blockIdx.x;
    const int f = bg >> 7, kxp = bg & 127;
    const int base = f * 524288 + kxp * 4096;
    const float alpha = dev_alpha(alpha_p);
    for (int i = tid; i < 4096; i += 256) {
        int kxo = i >> 11, rem = i & 2047;
        int ky = rem >> 3, d = rem & 7;
        int row = kxo * 8 + d;
        lre[row * RS + ky] = Fre[base + i] * alpha;
        lim[row * RS + ky] = Fim[base + i] * alpha;
    }
    __syncthreads();
    fft256_block(lre, lim, tid);
    for (int i = tid; i < 4096; i += 256) {
        int k = i >> 4, rr = i & 15;
        GTz[k * 32768 + f * 2048 + kxp * 16 + rr] = __floats2half2_rn(lre[rr * RS + k], lim[rr * RS + k]);
    }
}

// ---------------- dir z pass2: GTz[b][f][kx][d] -> FFT along kx -> Vz[(b*256+t)*128+c] ----------------
__global__ __launch_bounds__(256) void fft_pass2_z(
    const __half2* __restrict__ GTz, __half2* __restrict__ Vz)
{
    __shared__ float lre[16 * RS], lim[16 * RS];
    const int tid = threadIdx.x, bg = blockIdx.x;
    const int fp = bg & 7, b = bg >> 3;
    const int base = b * 32768 + fp * 4096;
    for (int i = tid; i < 4096; i += 256) {
        int fo = i >> 11, rem = i & 2047;
        int kx = rem >> 3, d = rem & 7;
        int row = fo * 8 + d;
        float2 v = __half22float2(GTz[base + i]);
        lre[row * RS + kx] = v.x;
        lim[row * RS + kx] = v.y;
    }
    __syncthreads();
    fft256_block(lre, lim, tid);
    for (int i = tid; i < 4096; i += 256) {
        int k = i >> 4, rr = i & 15;
        Vz[(b * 256 + k) * 128 + fp * 16 + rr] = __floats2half2_rn(lre[rr * RS + k], lim[rr * RS + k]);
    }
}

// ---------------- spatial sort (counting sort, key = zbin*256 + ybin) ----------------
__device__ __forceinline__ int bin8(float v) {
    return min(max((int)((v + 1.0f) * 127.5f), 0), 255);
}
__device__ __forceinline__ int pt_key(const float* pts, int pid) {
    float y = pts[pid * 3 + 1], z = pts[pid * 3 + 2];
    return bin8(z) * 256 + bin8(y);
}

__global__ __launch_bounds__(256) void zero_hist(unsigned* __restrict__ h) {
    h[blockIdx.x * 256 + threadIdx.x] = 0;
}
__global__ __launch_bounds__(256) void hist_k(const float* __restrict__ pts, unsigned* __restrict__ h) {
    int pid = blockIdx.x * 256 + threadIdx.x;
    atomicAdd(&h[pt_key(pts, pid)], 1u);
}
__global__ __launch_bounds__(256) void scan_k(const unsigned* __restrict__ h, unsigned* __restrict__ cur) {
    __shared__ unsigned part[256];
    const int t = threadIdx.x;
    unsigned sum = 0;
    for (int i = 0; i < 256; ++i) sum += h[t * 256 + i];
    part[t] = sum;
    __syncthreads();
    for (int o = 1; o < 256; o <<= 1) {
        unsigned v = part[t];
        unsigned add = (t >= o) ? part[t - o] : 0u;
        __syncthreads();
        part[t] = v + add;
        __syncthreads();
    }
    unsigned run = (t > 0) ? part[t - 1] : 0u;
    for (int i = 0; i < 256; ++i) {
        cur[t * 256 + i] = run;
        run += h[t * 256 + i];
    }
}
__global__ __launch_bounds__(256) void scatter_k(const float* __restrict__ pts,
                                                 unsigned* __restrict__ cur,
                                                 unsigned* __restrict__ perm) {
    int pid = blockIdx.x * 256 + threadIdx.x;
    unsigned pos = atomicAdd(&cur[pt_key(pts, pid)], 1u);
    perm[pos] = (unsigned)pid;
}

// ---------------- fused sampler: one wave per point, all 3 directions ----------------
__device__ __forceinline__ float4 bsample(const uint2* __restrict__ V,
                                          float gx, float gy, bool swap, int lane) {
    float ix = (gx + 1.0f) * 127.5f;
    float iy = (gy + 1.0f) * 127.5f;
    float x0f = floorf(ix), y0f = floorf(iy);
    float wx = ix - x0f, wy = iy - y0f;
    int x0 = min(max((int)x0f, 0), 255);
    int x1 = min(x0 + 1, 255);
    int y0 = min(max((int)y0f, 0), 255);
    int y1 = min(y0 + 1, 255);
    int rA, rB, rC, rD;
    if (swap) { rA = y0 * 256 + x0; rB = y0 * 256 + x1; rC = y1 * 256 + x0; rD = y1 * 256 + x1; }
    else      { rA = x0 * 256 + y0; rB = x1 * 256 + y0; rC = x0 * 256 + y1; rD = x1 * 256 + y1; }
    float w00 = (1.0f - wy) * (1.0f - wx);
    float w01 = (1.0f - wy) * wx;
    float w10 = wy * (1.0f - wx);
    float w11 = wy * wx;
    uint2 a = V[rA * 64 + lane];
    uint2 b = V[rB * 64 + lane];
    uint2 cc = V[rC * 64 + lane];
    uint2 dd = V[rD * 64 + lane];
    float4 s = make_float4(0.f, 0.f, 0.f, 0.f);
    float2 f0, f1;
    f0 = __half22float2(__builtin_bit_cast(__half2, a.x));  f1 = __half22float2(__builtin_bit_cast(__half2, a.y));
    s.x += w00 * f0.x; s.y += w00 * f0.y; s.z += w00 * f1.x; s.w += w00 * f1.y;
    f0 = __half22float2(__builtin_bit_cast(__half2, b.x));  f1 = __half22float2(__builtin_bit_cast(__half2, b.y));
    s.x += w01 * f0.x; s.y += w01 * f0.y; s.z += w01 * f1.x; s.w += w01 * f1.y;
    f0 = __half22float2(__builtin_bit_cast(__half2, cc.x)); f1 = __half22float2(__builtin_bit_cast(__half2, cc.y));
    s.x += w10 * f0.x; s.y += w10 * f0.y; s.z += w10 * f1.x; s.w += w10 * f1.y;
    f0 = __half22float2(__builtin_bit_cast(__half2, dd.x)); f1 = __half22float2(__builtin_bit_cast(__half2, dd.y));
    s.x += w11 * f0.x; s.y += w11 * f0.y; s.z += w11 * f1.x; s.w += w11 * f1.y;
    return s;
}

__device__ __forceinline__ float irdft(float4 s, float tw, int lane) {
    const float TWO_PI = 6.28318530717958647692f;
    float xx = (tw + 1.0f) * 0.5f * (255.0f / 256.0f);
    int k0 = (lane & 3) * 2;
    float sa, ca, sb, cb;
    __sincosf(TWO_PI * xx * (float)k0,       &sa, &ca);
    __sincosf(TWO_PI * xx * (float)(k0 + 1), &sb, &cb);
    float sc0 = (k0 > 0) ? 2.0f : 1.0f;
    return sc0 * (s.x * ca - s.y * sa) + 2.0f * (s.z * cb - s.w * sb);
}

__global__ __launch_bounds__(256) void sample_all(
    const uint2* __restrict__ Vx, const uint2* __restrict__ Vy, const uint2* __restrict__ Vz,
    const float* __restrict__ pts, const unsigned* __restrict__ perm,
    float* __restrict__ out)
{
    const int wid  = (int)((blockIdx.x * blockDim.x + threadIdx.x) >> 6);
    const int lane = threadIdx.x & 63;
    if (wid >= NPTS) return;
    const int pid = perm ? (int)perm[wid] : wid;
    const float xs = pts[pid * 3 + 0];
    const float ys = pts[pid * 3 + 1];
    const float zs = pts[pid * 3 + 2];

    float4 sx = bsample(Vx, zs, ys, false, lane);
    float4 sy = bsample(Vy, zs, xs, false, lane);
    float4 sz = bsample(Vz, xs, ys, true, lane);

    float p = irdft(sx, xs, lane) + irdft(sy, ys, lane) + irdft(sz, zs, lane);
    p += __shfl_xor(p, 1, 64);
    p += __shfl_xor(p, 2, 64);
    if ((lane & 3) == 0) out[pid * 16 + (lane >> 2)] = p;
}

extern "C" void kernel_launch(void* const* d_in, const int* in_sizes, int n_in,
                              void* d_out, int out_size, void* d_ws, size_t ws_size,
                              hipStream_t stream) {
    const float* pts     = (const float*)d_in[0];
    const float* Fx_re   = (const float*)d_in[1];
    const float* Fx_im   = (const float*)d_in[2];
    const float* Fy_re   = (const float*)d_in[3];
    const float* Fy_im   = (const float*)d_in[4];
    const float* Fz_re   = (const float*)d_in[5];
    const float* Fz_im   = (const float*)d_in[6];
    const float* alpha_p = (const float*)d_in[7];
    float* out = (float*)d_out;

    char* ws = (char*)d_ws;
    const size_t MB = 1024 * 1024;
    __half2* Vx = (__half2*)(ws);
    __half2* Vy = (__half2*)(ws + 32 * MB);
    __half2* Vz = (__half2*)(ws + 64 * MB);
    __half2* GT = (__half2*)(ws + 96 * MB);
    unsigned* hist = (unsigned*)(ws + 128 * MB);             // 256 KB
    unsigned* cur  = (unsigned*)(ws + 128 * MB + 256 * 1024); // 256 KB
    unsigned* perm = (unsigned*)(ws + 128 * MB + 512 * 1024); // 512 KB
    const bool do_sort = ws_size >= 129 * MB + 64 * 1024;

    if (do_sort) {
        zero_hist<<<256, 256, 0, stream>>>(hist);
        hist_k<<<NPTS / 256, 256, 0, stream>>>(pts, hist);
        scan_k<<<1, 256, 0, stream>>>(hist, cur);
        scatter_k<<<NPTS / 256, 256, 0, stream>>>(pts, cur, perm);
    }

    // dir x: F[f][d][ky][kz]: Sd=65536, Sa(ky)=256 ; pass1 FFT kz, pass2 FFT ky
    fft_pass1_xy<<<2048, 256, 0, stream>>>(Fx_re, Fx_im, alpha_p, GT, 65536, 256);
    fft_pass2_xy<<<2048, 256, 0, stream>>>(GT, Vx);
    // dir y: F[f][kx][d][kz]: Sd=256, Sa(kx)=2048 ; pass1 FFT kz, pass2 FFT kx
    fft_pass1_xy<<<2048, 256, 0, stream>>>(Fy_re, Fy_im, alpha_p, GT, 256, 2048);
    fft_pass2_xy<<<2048, 256, 0, stream>>>(GT, Vy);
    // dir z: contiguous-load specialized kernels
    fft_pass1_z<<<2048, 256, 0, stream>>>(Fz_re, Fz_im, alpha_p, GT);
    fft_pass2_z<<<2048, 256, 0, stream>>>(GT, Vz);

    sample_all<<<NPTS / 4, 256, 0, stream>>>((const uint2*)Vx, (const uint2*)Vy, (const uint2*)Vz,
                                             pts, do_sort ? perm : (const unsigned*)nullptr, out);
}

// Round 4
// 384.021 us; speedup vs baseline: 1.9678x; 1.1203x over previous
//
#include <hip/hip_runtime.h>
#include <hip/hip_fp16.h>
#include <math.h>

#define NPTS 131072
#define RS 264  // LDS row stride in floats; 264*4B = 16B-aligned rows, banks spread by 8/row

__device__ __forceinline__ float dev_alpha(const float* __restrict__ ap) {
    float x = ap[0];
    float bx = 10.0f * x;
    if (bx > 1.0f) return x;
    float e = expf(fminf(bx, 30.0f));
    return 0.1f * log1pf(e);
}

// -------- 16-point inverse DFT (e^{+i}) in registers, natural in/out --------
__device__ __forceinline__ void fft16_reg(float* re, float* im) {
    #define SW(a,b) { float t=re[a]; re[a]=re[b]; re[b]=t; t=im[a]; im[a]=im[b]; im[b]=t; }
    SW(1,8) SW(2,4) SW(3,12) SW(5,10) SW(7,14) SW(11,13)
    #undef SW
    const float C[8] = {1.f, 0.9238795325112867f, 0.7071067811865476f, 0.3826834323650898f,
                        0.f, -0.3826834323650898f, -0.7071067811865476f, -0.9238795325112867f};
    const float S[8] = {0.f, 0.3826834323650898f, 0.7071067811865476f, 0.9238795325112867f,
                        1.f, 0.9238795325112867f, 0.7071067811865476f, 0.3826834323650898f};
    #pragma unroll
    for (int m = 1; m < 16; m <<= 1) {
        #pragma unroll
        for (int k = 0; k < 16; k += 2 * m) {
            #pragma unroll
            for (int j = 0; j < m; ++j) {
                float wc = C[j * (8 / m)], ws = S[j * (8 / m)];
                int i0 = k + j, i1 = i0 + m;
                float tr = re[i1] * wc - im[i1] * ws;
                float ti = re[i1] * ws + im[i1] * wc;
                re[i1] = re[i0] - tr; im[i1] = im[i0] - ti;
                re[i0] += tr;         im[i0] += ti;
            }
        }
    }
}

// -------- 256-pt inverse FFT over 16 rows staged in LDS (natural in, natural out) --------
__device__ __forceinline__ void fft256_block(float* lre, float* lim, int tid) {
    const int r = tid >> 4, s = tid & 15;
    float xr[16], xi[16];
    #pragma unroll
    for (int a = 0; a < 16; ++a) {
        xr[a] = lre[r * RS + 16 * a + s];
        xi[a] = lim[r * RS + 16 * a + s];
    }
    __syncthreads();
    fft16_reg(xr, xi);
    #pragma unroll
    for (int c = 0; c < 16; ++c) {
        float sn, cs;
        __sincosf(0.0245436926061703f * (float)(s * c), &sn, &cs); // 2*pi/256
        float tr = xr[c] * cs - xi[c] * sn;
        float ti = xr[c] * sn + xi[c] * cs;
        int idx = r * RS + 16 * c + (s ^ c);
        lre[idx] = tr; lim[idx] = ti;
    }
    __syncthreads();
    #pragma unroll
    for (int b = 0; b < 16; ++b) {
        int idx = r * RS + 16 * s + (b ^ s);
        xr[b] = lre[idx]; xi[b] = lim[idx];
    }
    __syncthreads();
    fft16_reg(xr, xi);
    #pragma unroll
    for (int d = 0; d < 16; ++d) {
        int idx = r * RS + 16 * d + s;
        lre[idx] = xr[d]; lim[idx] = xi[d];
    }
    __syncthreads();
}

__device__ __forceinline__ unsigned packh2(float re, float im) {
    return __builtin_bit_cast(unsigned, __floats2half2_rn(re, im));
}

// ---------------- pass1 (dirs x,y): FFT along innermost b, GT[c][b][a] fp16 ----------------
__global__ __launch_bounds__(256) void fft_pass1_xy(
    const float4* __restrict__ Fre4, const float4* __restrict__ Fim4,
    const float* __restrict__ alpha_p, uint4* __restrict__ GT4,
    int Sd4, int Sa4)
{
    __shared__ float lre[16 * RS], lim[16 * RS];
    const int tid = threadIdx.x, bg = blockIdx.x;
    const int d = bg & 7, ag = (bg >> 3) & 15, f = bg >> 7;
    const int a0 = ag * 16, c = f * 8 + d;
    const int base4 = f * 131072 + d * Sd4 + a0 * Sa4;
    const float alpha = dev_alpha(alpha_p);
    #pragma unroll
    for (int j = 0; j < 4; ++j) {
        int i4 = tid + 256 * j;
        int ar = i4 >> 6, b4 = i4 & 63;
        float4 vr = Fre4[base4 + ar * Sa4 + b4];
        float4 vi = Fim4[base4 + ar * Sa4 + b4];
        int o = ar * RS + 4 * b4;
        lre[o+0]=vr.x*alpha; lre[o+1]=vr.y*alpha; lre[o+2]=vr.z*alpha; lre[o+3]=vr.w*alpha;
        lim[o+0]=vi.x*alpha; lim[o+1]=vi.y*alpha; lim[o+2]=vi.z*alpha; lim[o+3]=vi.w*alpha;
    }
    __syncthreads();
    fft256_block(lre, lim, tid);
    const int g = tid >> 2, rq = tid & 3;
    #pragma unroll
    for (int j = 0; j < 4; ++j) {
        int k = g + 64 * j;
        uint4 ov;
        ov.x = packh2(lre[(4*rq+0)*RS+k], lim[(4*rq+0)*RS+k]);
        ov.y = packh2(lre[(4*rq+1)*RS+k], lim[(4*rq+1)*RS+k]);
        ov.z = packh2(lre[(4*rq+2)*RS+k], lim[(4*rq+2)*RS+k]);
        ov.w = packh2(lre[(4*rq+3)*RS+k], lim[(4*rq+3)*RS+k]);
        GT4[((c * 256 + k) * 256 + a0) / 4 + rq] = ov;
    }
}

// ---------------- pass2 (dirs x,y): FFT along a, V[b][t][c] fp16 ----------------
__global__ __launch_bounds__(256) void fft_pass2_xy(
    const uint4* __restrict__ GT4, uint4* __restrict__ V4)
{
    __shared__ float lre[16 * RS], lim[16 * RS];
    const int tid = threadIdx.x, bg = blockIdx.x;
    const int cg = bg & 7, b = bg >> 3, c0 = cg * 16;
    #pragma unroll
    for (int j = 0; j < 4; ++j) {
        int i4 = tid + 256 * j;
        int cr = i4 >> 6, a4 = i4 & 63;
        uint4 gv = GT4[(((c0 + cr) * 256 + b) * 256) / 4 + a4];
        int o = cr * RS + 4 * a4;
        float2 e;
        e = __half22float2(__builtin_bit_cast(__half2, gv.x)); lre[o+0]=e.x; lim[o+0]=e.y;
        e = __half22float2(__builtin_bit_cast(__half2, gv.y)); lre[o+1]=e.x; lim[o+1]=e.y;
        e = __half22float2(__builtin_bit_cast(__half2, gv.z)); lre[o+2]=e.x; lim[o+2]=e.y;
        e = __half22float2(__builtin_bit_cast(__half2, gv.w)); lre[o+3]=e.x; lim[o+3]=e.y;
    }
    __syncthreads();
    fft256_block(lre, lim, tid);
    const int g = tid >> 2, cq = tid & 3;
    #pragma unroll
    for (int j = 0; j < 4; ++j) {
        int k = g + 64 * j;
        uint4 ov;
        ov.x = packh2(lre[(4*cq+0)*RS+k], lim[(4*cq+0)*RS+k]);
        ov.y = packh2(lre[(4*cq+1)*RS+k], lim[(4*cq+1)*RS+k]);
        ov.z = packh2(lre[(4*cq+2)*RS+k], lim[(4*cq+2)*RS+k]);
        ov.w = packh2(lre[(4*cq+3)*RS+k], lim[(4*cq+3)*RS+k]);
        V4[((b * 256 + k) * 128 + c0) / 4 + cq] = ov;
    }
}

// ---------------- dir z pass1: Fz[f][kx][ky][d] -> FFT along ky -> GTz[b][f][kx][d] ----------------
__global__ __launch_bounds__(256) void fft_pass1_z(
    const float4* __restrict__ Fre4, const float4* __restrict__ Fim4,
    const float* __restrict__ alpha_p, uint4* __restrict__ GTz4)
{
    __shared__ float lre[16 * RS], lim[16 * RS];
    const int tid = threadIdx.x, bg = blockIdx.x;
    const int f = bg >> 7, kxp = bg & 127;
    const int base4 = f * 131072 + kxp * 1024;
    const float alpha = dev_alpha(alpha_p);
    #pragma unroll
    for (int j = 0; j < 4; ++j) {
        int i4 = tid + 256 * j;
        int kxo = i4 >> 9, ky = (i4 & 511) >> 1, t0 = i4 & 1;
        float4 vr = Fre4[base4 + i4];
        float4 vi = Fim4[base4 + i4];
        int row = kxo * 8 + 4 * t0;
        lre[(row+0)*RS + ky] = vr.x*alpha; lim[(row+0)*RS + ky] = vi.x*alpha;
        lre[(row+1)*RS + ky] = vr.y*alpha; lim[(row+1)*RS + ky] = vi.y*alpha;
        lre[(row+2)*RS + ky] = vr.z*alpha; lim[(row+2)*RS + ky] = vi.z*alpha;
        lre[(row+3)*RS + ky] = vr.w*alpha; lim[(row+3)*RS + ky] = vi.w*alpha;
    }
    __syncthreads();
    fft256_block(lre, lim, tid);
    const int g = tid >> 2, rq = tid & 3;
    #pragma unroll
    for (int j = 0; j < 4; ++j) {
        int k = g + 64 * j;
        uint4 ov;
        ov.x = packh2(lre[(4*rq+0)*RS+k], lim[(4*rq+0)*RS+k]);
        ov.y = packh2(lre[(4*rq+1)*RS+k], lim[(4*rq+1)*RS+k]);
        ov.z = packh2(lre[(4*rq+2)*RS+k], lim[(4*rq+2)*RS+k]);
        ov.w = packh2(lre[(4*rq+3)*RS+k], lim[(4*rq+3)*RS+k]);
        GTz4[k * 8192 + f * 512 + kxp * 4 + rq] = ov;
    }
}

// ---------------- dir z pass2: GTz[b][f][kx][d] -> FFT along kx -> Vz[b][t][c] ----------------
__global__ __launch_bounds__(256) void fft_pass2_z(
    const uint4* __restrict__ GTz4, uint4* __restrict__ V4)
{
    __shared__ float lre[16 * RS], lim[16 * RS];
    const int tid = threadIdx.x, bg = blockIdx.x;
    const int fp = bg & 7, b = bg >> 3;
    const int base4 = b * 8192 + fp * 1024;
    #pragma unroll
    for (int j = 0; j < 4; ++j) {
        int i4 = tid + 256 * j;
        int fo = i4 >> 9, kx = (i4 & 511) >> 1, t0 = i4 & 1;
        uint4 gv = GTz4[base4 + i4];
        int row = fo * 8 + 4 * t0;
        float2 e;
        e = __half22float2(__builtin_bit_cast(__half2, gv.x)); lre[(row+0)*RS+kx]=e.x; lim[(row+0)*RS+kx]=e.y;
        e = __half22float2(__builtin_bit_cast(__half2, gv.y)); lre[(row+1)*RS+kx]=e.x; lim[(row+1)*RS+kx]=e.y;
        e = __half22float2(__builtin_bit_cast(__half2, gv.z)); lre[(row+2)*RS+kx]=e.x; lim[(row+2)*RS+kx]=e.y;
        e = __half22float2(__builtin_bit_cast(__half2, gv.w)); lre[(row+3)*RS+kx]=e.x; lim[(row+3)*RS+kx]=e.y;
    }
    __syncthreads();
    fft256_block(lre, lim, tid);
    const int g = tid >> 2, rq = tid & 3;
    #pragma unroll
    for (int j = 0; j < 4; ++j) {
        int k = g + 64 * j;
        uint4 ov;
        ov.x = packh2(lre[(4*rq+0)*RS+k], lim[(4*rq+0)*RS+k]);
        ov.y = packh2(lre[(4*rq+1)*RS+k], lim[(4*rq+1)*RS+k]);
        ov.z = packh2(lre[(4*rq+2)*RS+k], lim[(4*rq+2)*RS+k]);
        ov.w = packh2(lre[(4*rq+3)*RS+k], lim[(4*rq+3)*RS+k]);
        V4[(b * 256 + k) * 32 + fp * 4 + rq] = ov;
    }
}

// ---------------- spatial sort (counting sort, key = zbin*256 + ybin) ----------------
__device__ __forceinline__ int bin8(float v) {
    return min(max((int)((v + 1.0f) * 127.5f), 0), 255);
}
__global__ __launch_bounds__(256) void zero_hist(unsigned* __restrict__ h) {
    h[blockIdx.x * 256 + threadIdx.x] = 0;
}
__global__ __launch_bounds__(256) void hist_k(const float* __restrict__ pts, unsigned* __restrict__ h) {
    int pid = blockIdx.x * 256 + threadIdx.x;
    int key = bin8(pts[pid * 3 + 2]) * 256 + bin8(pts[pid * 3 + 1]);
    atomicAdd(&h[key], 1u);
}
__global__ __launch_bounds__(256) void scan_k(const unsigned* __restrict__ h, unsigned* __restrict__ cur) {
    __shared__ unsigned part[256];
    const int t = threadIdx.x;
    unsigned sum = 0;
    for (int i = 0; i < 256; ++i) sum += h[t * 256 + i];
    part[t] = sum;
    __syncthreads();
    for (int o = 1; o < 256; o <<= 1) {
        unsigned v = part[t];
        unsigned add = (t >= o) ? part[t - o] : 0u;
        __syncthreads();
        part[t] = v + add;
        __syncthreads();
    }
    unsigned run = (t > 0) ? part[t - 1] : 0u;
    for (int i = 0; i < 256; ++i) {
        cur[t * 256 + i] = run;
        run += h[t * 256 + i];
    }
}
__global__ __launch_bounds__(256) void scatter_k(const float* __restrict__ pts,
                                                 unsigned* __restrict__ cur,
                                                 float4* __restrict__ ptsS) {
    int pid = blockIdx.x * 256 + threadIdx.x;
    float x = pts[pid * 3 + 0], y = pts[pid * 3 + 1], z = pts[pid * 3 + 2];
    int key = bin8(z) * 256 + bin8(y);
    unsigned pos = atomicAdd(&cur[key], 1u);
    ptsS[pos] = make_float4(x, y, z, __uint_as_float((unsigned)pid));
}

// ---------------- fused sampler ----------------
__device__ __forceinline__ float4 bsample(const uint2* __restrict__ V,
                                          float gx, float gy, bool swap, int lane) {
    float ix = (gx + 1.0f) * 127.5f;
    float iy = (gy + 1.0f) * 127.5f;
    float x0f = floorf(ix), y0f = floorf(iy);
    float wx = ix - x0f, wy = iy - y0f;
    int x0 = min(max((int)x0f, 0), 255);
    int x1 = min(x0 + 1, 255);
    int y0 = min(max((int)y0f, 0), 255);
    int y1 = min(y0 + 1, 255);
    int rA, rB, rC, rD;
    if (swap) { rA = y0*256+x0; rB = y0*256+x1; rC = y1*256+x0; rD = y1*256+x1; }
    else      { rA = x0*256+y0; rB = x1*256+y0; rC = x0*256+y1; rD = x1*256+y1; }
    uint2 a = V[rA * 64 + lane];
    uint2 b = V[rB * 64 + lane];
    uint2 c = V[rC * 64 + lane];
    uint2 d = V[rD * 64 + lane];
    __half2 w00 = __float2half2_rn((1.0f - wy) * (1.0f - wx));
    __half2 w01 = __float2half2_rn((1.0f - wy) * wx);
    __half2 w10 = __float2half2_rn(wy * (1.0f - wx));
    __half2 w11 = __float2half2_rn(wy * wx);
    __half2 acc0 = __hmul2(w00, __builtin_bit_cast(__half2, a.x));
    __half2 acc1 = __hmul2(w00, __builtin_bit_cast(__half2, a.y));
    acc0 = __hfma2(w01, __builtin_bit_cast(__half2, b.x), acc0);
    acc1 = __hfma2(w01, __builtin_bit_cast(__half2, b.y), acc1);
    acc0 = __hfma2(w10, __builtin_bit_cast(__half2, c.x), acc0);
    acc1 = __hfma2(w10, __builtin_bit_cast(__half2, c.y), acc1);
    acc0 = __hfma2(w11, __builtin_bit_cast(__half2, d.x), acc0);
    acc1 = __hfma2(w11, __builtin_bit_cast(__half2, d.y), acc1);
    return make_float4(__low2float(acc0), __high2float(acc0),
                       __low2float(acc1), __high2float(acc1));
}

__device__ __forceinline__ float irdft(float4 s, float tw, int lane) {
    const float TWO_PI = 6.28318530717958647692f;
    float xx = (tw + 1.0f) * 0.5f * (255.0f / 256.0f);
    int k0 = (lane & 3) * 2;
    float sa, ca, sb, cb;
    __sincosf(TWO_PI * xx * (float)k0,       &sa, &ca);
    __sincosf(TWO_PI * xx * (float)(k0 + 1), &sb, &cb);
    float sc0 = (k0 > 0) ? 2.0f : 1.0f;
    return sc0 * (s.x * ca - s.y * sa) + 2.0f * (s.z * cb - s.w * sb);
}

__global__ __launch_bounds__(256) void sample_all(
    const uint2* __restrict__ Vx, const uint2* __restrict__ Vy, const uint2* __restrict__ Vz,
    const float4* __restrict__ ptsS, float* __restrict__ out)
{
    const int lb = blockIdx.x;
    const int chunk = (lb & 7) * 4096 + (lb >> 3);  // XCD-contiguous point ranges
    const int wid = chunk * 4 + ((int)threadIdx.x >> 6);
    const int lane = threadIdx.x & 63;
    float4 p = ptsS[wid];
    const float xs = p.x, ys = p.y, zs = p.z;
    const int pid = (int)__float_as_uint(p.w);

    float4 sx = bsample(Vx, zs, ys, false, lane);
    float4 sy = bsample(Vy, zs, xs, false, lane);
    float4 sz = bsample(Vz, xs, ys, true, lane);

    float pv = irdft(sx, xs, lane) + irdft(sy, ys, lane) + irdft(sz, zs, lane);
    pv += __shfl_xor(pv, 1, 64);
    pv += __shfl_xor(pv, 2, 64);
    if ((lane & 3) == 0) out[pid * 16 + (lane >> 2)] = pv;
}

extern "C" void kernel_launch(void* const* d_in, const int* in_sizes, int n_in,
                              void* d_out, int out_size, void* d_ws, size_t ws_size,
                              hipStream_t stream) {
    const float* pts     = (const float*)d_in[0];
    const float* Fx_re   = (const float*)d_in[1];
    const float* Fx_im   = (const float*)d_in[2];
    const float* Fy_re   = (const float*)d_in[3];
    const float* Fy_im   = (const float*)d_in[4];
    const float* Fz_re   = (const float*)d_in[5];
    const float* Fz_im   = (const float*)d_in[6];
    const float* alpha_p = (const float*)d_in[7];
    float* out = (float*)d_out;

    char* ws = (char*)d_ws;
    const size_t MB = 1024 * 1024;
    uint4* Vx4 = (uint4*)(ws);
    uint4* Vy4 = (uint4*)(ws + 32 * MB);
    uint4* Vz4 = (uint4*)(ws + 64 * MB);
    uint4* GT4 = (uint4*)(ws + 96 * MB);   // 32 MiB, reused per dir by FFTs
    // sort scratch lives inside the GT region; sort runs AFTER all FFTs
    unsigned* hist = (unsigned*)(ws + 96 * MB);
    unsigned* cur  = (unsigned*)(ws + 96 * MB + 256 * 1024);
    float4*   ptsS = (float4*)  (ws + 96 * MB + 512 * 1024); // 2 MiB

    // dir x: F[f][d][ky][kz]: Sd4=16384, Sa4(ky)=64 ; pass1 FFT kz, pass2 FFT ky
    fft_pass1_xy<<<2048, 256, 0, stream>>>((const float4*)Fx_re, (const float4*)Fx_im, alpha_p, GT4, 16384, 64);
    fft_pass2_xy<<<2048, 256, 0, stream>>>(GT4, Vx4);
    // dir y: F[f][kx][d][kz]: Sd4=64, Sa4(kx)=512 ; pass1 FFT kz, pass2 FFT kx
    fft_pass1_xy<<<2048, 256, 0, stream>>>((const float4*)Fy_re, (const float4*)Fy_im, alpha_p, GT4, 64, 512);
    fft_pass2_xy<<<2048, 256, 0, stream>>>(GT4, Vy4);
    // dir z: contiguous-load specialized kernels
    fft_pass1_z<<<2048, 256, 0, stream>>>((const float4*)Fz_re, (const float4*)Fz_im, alpha_p, GT4);
    fft_pass2_z<<<2048, 256, 0, stream>>>(GT4, Vz4);

    // spatial sort (scratch overlaps GT, safe after FFTs)
    zero_hist<<<256, 256, 0, stream>>>(hist);
    hist_k<<<NPTS / 256, 256, 0, stream>>>(pts, hist);
    scan_k<<<1, 256, 0, stream>>>(hist, cur);
    scatter_k<<<NPTS / 256, 256, 0, stream>>>(pts, cur, ptsS);

    sample_all<<<NPTS / 4, 256, 0, stream>>>((const uint2*)Vx4, (const uint2*)Vy4, (const uint2*)Vz4,
                                             ptsS, out);
}